// Round 1
// baseline (278.396 us; speedup 1.0000x reference)
//
#include <hip/hip_runtime.h>
#include <cstdint>

#define D 128
#define T 64
#define B 512
#define EPSF 1e-5f

// wave-uniform lane broadcast via v_readlane (no LDS/ds_bpermute)
__device__ __forceinline__ float lane_bcast(float x, int l) {
    return __int_as_float(__builtin_amdgcn_readlane(__float_as_int(x), l));
}

// ---------------------------------------------------------------------------
// prep: vT[k*D+i] = v[i][k] = W[i][k]/max(norm_i,1e-12); vd[i]=v[i][i]; absb=|b|
// ---------------------------------------------------------------------------
__global__ __launch_bounds__(64) void prep_kernel(const float* __restrict__ W,
                                                  const float* __restrict__ b,
                                                  float* __restrict__ vT,
                                                  float* __restrict__ vd,
                                                  float* __restrict__ absb) {
    const int i = blockIdx.x;
    const int l = threadIdx.x;
    float w0 = W[i * D + l];
    float w1 = W[i * D + l + 64];
    float p = w0 * w0 + w1 * w1;
#pragma unroll
    for (int off = 32; off; off >>= 1) p += __shfl_xor(p, off);
    float norm = sqrtf(p);
    float scale = norm > 1e-12f ? norm : 1e-12f;
    float v0 = w0 / scale;
    float v1 = w1 / scale;
    vT[l * D + i] = v0;
    vT[(l + 64) * D + i] = v1;
    if (i < 64) {
        if (l == i) vd[i] = v0;
    } else {
        if (l == i - 64) vd[i] = v1;
    }
    if (i == 0) {
        absb[l] = fabsf(b[l]);
        absb[l + 64] = fabsf(b[l + 64]);
    }
}

// ---------------------------------------------------------------------------
// main RNN kernel. 2 waves/block, wave w owns batch column b = 2*blockIdx + w
// (state rows lane, lane+64), exactly as before. NEW: the s = v@(adj-pi_bar)
// matvec is computed cooperatively: wave w computes s-rows [64w,64w+64) for
// BOTH columns from a row-major LDS copy of v (float4 reads, conflict-free
// XOR swizzle) against x staged in LDS (uniform-address b128 = broadcast).
// Accumulation order over k is unchanged -> bit-identical numerics.
//
// v lives in LDS twice (129.5 KB total; grid = 256 blocks = 1 block/CU on a
// 160 KB/CU chip, so the extra LDS costs nothing):
//   vrow [i*128 + (k ^ ((i&7)<<2))] = v[i][k]        row-major, b128 matvec
//   vpair[k*64  + (i ^ ((k&3)<<2))] = {v[i][k],      column pairs: sweep and
//                                      v[i+64][k]}   probe get both rows in
//                                                    one b64; judge b128 cols
// ---------------------------------------------------------------------------
__global__ __launch_bounds__(128) void rnn_kernel(const float* __restrict__ input,
                                                  const float* __restrict__ target,
                                                  const float* __restrict__ returns,
                                                  const float* __restrict__ vTg,
                                                  const float* __restrict__ vdg,
                                                  const float* __restrict__ absbg,
                                                  float* __restrict__ out) {
    __shared__ __align__(16) float  vrow[D * D];    // 64 KB
    __shared__ __align__(16) float2 vpair[D * 64];  // 64 KB
    __shared__ __align__(16) float  xsh[2][D];      // 1 KB
    __shared__ float ssh[2][64];                    // 0.5 KB

    const int tid = threadIdx.x;
    const int lane = tid & 63;
    const int wid = tid >> 6;

    // ---- build both LDS layouts from plain vT (one-time) ----
#pragma unroll
    for (int c = 0; c < 32; ++c) {
        int f = c * 128 + tid;          // float4 index into vpair (0..4095)
        int k = f >> 5;                 // column of v
        int i0 = (f & 31) << 1;         // even logical pair index
        float4 val;
        val.x = vTg[k * D + i0];
        val.y = vTg[k * D + i0 + 64];
        val.z = vTg[k * D + i0 + 1];
        val.w = vTg[k * D + i0 + 65];
        *(float4*)&vpair[(k << 6) + (i0 ^ ((k & 3) << 2))] = val;
    }
#pragma unroll
    for (int c = 0; c < 32; ++c) {
        int f = c * 128 + tid;          // float4 index into vrow (0..4095)
        int i = f >> 5;                 // row of v
        int k0 = (f & 31) << 2;
        float4 val;
        val.x = vTg[k0 * D + i];
        val.y = vTg[(k0 + 1) * D + i];
        val.z = vTg[(k0 + 2) * D + i];
        val.w = vTg[(k0 + 3) * D + i];
        *(float4*)&vrow[i * D + (k0 ^ ((i & 7) << 2))] = val;
    }
    __syncthreads();

    const int b = blockIdx.x * 2 + wid;
    const int rlo = lane, rhi = lane + 64;
    const int mrow = wid * 64 + lane;          // s-row this thread computes
    const float* vr = &vrow[mrow * D];
    const int swr = (mrow & 7) << 2;

    const float tgt_lo = target[rlo], tgt_hi = target[rhi];
    const float a_lo = absbg[rlo], a_hi = absbg[rhi];
    const float aeps_lo = a_lo + EPSF, aeps_hi = a_hi + EPSF;
    const float vd_lo = vdg[rlo], vd_hi = vdg[rhi];
    const float rvd_lo = 1.0f / vd_lo, rvd_hi = 1.0f / vd_hi;

    float h_lo = input[rlo * T * B + b];
    float h_hi = input[rhi * T * B + b];
    out[rlo * T * B + b] = h_lo;
    out[rhi * T * B + b] = h_hi;

    float r_lo = returns[rlo * T * B + b];
    float r_hi = returns[rhi * T * B + b];

    for (int t = 1; t < T; ++t) {
        // ---- adj = h*(1+r)/(1 + sum(h*r)) (each wave: its own column) ----
        float num_lo = h_lo * (1.0f + r_lo);
        float num_hi = h_hi * (1.0f + r_hi);
        float p = h_lo * r_lo + h_hi * r_hi;
#pragma unroll
        for (int off = 32; off; off >>= 1) p += __shfl_xor(p, off);
        float den = 1.0f + p;
        float adj_lo = num_lo / den;
        float adj_hi = num_hi / den;

        if (t < T - 1) {
            r_lo = returns[rlo * T * B + t * B + b];
            r_hi = returns[rhi * T * B + t * B + b];
        }

        float x_lo = adj_lo - tgt_lo;
        float x_hi = adj_hi - tgt_hi;
        xsh[wid][rlo] = x_lo;
        xsh[wid][rhi] = x_hi;
        h_lo = adj_lo;
        h_hi = adj_hi;

        __syncthreads();   // A: xsh ready for both columns

        // ---- cooperative matvec: rows [64*wid, 64*wid+64) for BOTH cols ----
        // k ascending, single accumulator per (row,col): identical order to
        // the original per-column loop -> bit-identical s.
        float s0 = 0.0f, s1 = 0.0f;
#pragma unroll
        for (int k4 = 0; k4 < D; k4 += 4) {
            float4 vv = *(const float4*)&vr[k4 ^ swr];
            float4 x0 = *(const float4*)&xsh[0][k4];
            float4 x1 = *(const float4*)&xsh[1][k4];
            s0 = fmaf(vv.x, x0.x, s0);
            s0 = fmaf(vv.y, x0.y, s0);
            s0 = fmaf(vv.z, x0.z, s0);
            s0 = fmaf(vv.w, x0.w, s0);
            s1 = fmaf(vv.x, x1.x, s1);
            s1 = fmaf(vv.y, x1.y, s1);
            s1 = fmaf(vv.z, x1.z, s1);
            s1 = fmaf(vv.w, x1.w, s1);
        }
        // wave0 holds rows 0-63 (s_lo of col0 = s0), misses s_hi of col0;
        // wave1 holds rows 64-127 (s_hi of col1 = s1), misses s_lo of col1.
        ssh[wid ^ 1][lane] = wid ? s0 : s1;   // give the other col its half

        __syncthreads();   // B: ssh ready

        float miss = ssh[wid][lane];
        float s_lo = wid ? miss : s0;
        float s_hi = wid ? s1 : miss;

        // ================= correction (wave-local, logic unchanged) ========
        bool viol_lo = (s_lo > a_lo) || (s_lo < -a_lo);
        bool viol_hi = (s_hi > a_hi) || (s_hi < -a_hi);
        uint64_t mlo = __ballot(viol_lo);
        uint64_t mhi = __ballot(viol_hi);

        if ((mlo | mhi) != 0ull) {
            // per-lane deltas (reference lam formulas, IEEE div)
            float dl = 0.0f, dh = 0.0f;
            if (s_lo > a_lo) dl = (a_lo - s_lo) / vd_lo;
            else if (s_lo < -a_lo) dl = (-a_lo - s_lo) / vd_lo;
            if (s_hi > a_hi) dh = (a_hi - s_hi) / vd_hi;
            else if (s_hi < -a_hi) dh = (-a_hi - s_hi) / vd_hi;

            int V = __popcll(mlo) + __popcll(mhi);
            bool judge;

            if (V <= 8) {
                // q0: all strictly inside a+eps (zero-delta column exists)
                bool in_lo = (s_lo < aeps_lo) && (s_lo > -aeps_lo);
                bool in_hi = (s_hi < aeps_hi) && (s_hi > -aeps_hi);
                judge = (__ballot(in_lo && in_hi) == ~0ull);
                if (!judge) {
                    uint64_t t_mlo = mlo, t_mhi = mhi;
                    while (t_mlo | t_mhi) {
                        int j;
                        float dj;
                        if (t_mlo) {
                            int jl = (int)__ffsll((unsigned long long)t_mlo) - 1;
                            t_mlo &= t_mlo - 1;
                            j = jl;
                            dj = lane_bcast(dl, jl);
                        } else {
                            int jh = (int)__ffsll((unsigned long long)t_mhi) - 1;
                            t_mhi &= t_mhi - 1;
                            j = 64 + jh;
                            dj = lane_bcast(dh, jh);
                        }
                        float2 vj = vpair[(j << 6) + (lane ^ ((j & 3) << 2))];
                        float n_lo = fmaf(vj.x, dj, s_lo);
                        float n_hi = fmaf(vj.y, dj, s_hi);
                        bool pl = (n_lo < aeps_lo) && (n_lo > -aeps_lo);
                        bool ph = (n_hi < aeps_hi) && (n_hi > -aeps_hi);
                        if (__ballot(pl && ph) == ~0ull) { judge = true; break; }
                    }
                }
            } else {
                // ---- parallel judge: lane tests candidates j=lane, lane+64.
                // vpair float4 covers rows ii, ii+64, ii+1, ii+65 at once.
                // fmax is exact/order-free -> 2 accumulators per candidate.
                float m1a = -1.0f, m1b = -1.0f, m2a = -1.0f, m2b = -1.0f;
                const float2* r1 = vpair + (lane << 6);
                const float2* r2 = vpair + ((lane + 64) << 6);
                const int swj = (lane & 3) << 2;
#pragma unroll
                for (int ii = 0; ii < 64; ii += 2) {
                    const int ix = ii ^ swj;
                    float4 c1 = *(const float4*)(r1 + ix);
                    float4 c2 = *(const float4*)(r2 + ix);
                    float sl0 = lane_bcast(s_lo, ii), sh0 = lane_bcast(s_hi, ii);
                    float sl1 = lane_bcast(s_lo, ii + 1), sh1 = lane_bcast(s_hi, ii + 1);
                    float al0 = lane_bcast(aeps_lo, ii), ah0 = lane_bcast(aeps_hi, ii);
                    float al1 = lane_bcast(aeps_lo, ii + 1), ah1 = lane_bcast(aeps_hi, ii + 1);
                    m1a = fmaxf(m1a, fabsf(fmaf(c1.x, dl, sl0)) - al0);
                    m1b = fmaxf(m1b, fabsf(fmaf(c1.y, dl, sh0)) - ah0);
                    m1a = fmaxf(m1a, fabsf(fmaf(c1.z, dl, sl1)) - al1);
                    m1b = fmaxf(m1b, fabsf(fmaf(c1.w, dl, sh1)) - ah1);
                    m2a = fmaxf(m2a, fabsf(fmaf(c2.x, dh, sl0)) - al0);
                    m2b = fmaxf(m2b, fabsf(fmaf(c2.y, dh, sh0)) - ah0);
                    m2a = fmaxf(m2a, fabsf(fmaf(c2.z, dh, sl1)) - al1);
                    m2b = fmaxf(m2b, fabsf(fmaf(c2.w, dh, sh1)) - ah1);
                }
                float m1 = fmaxf(m1a, m1b);
                float m2 = fmaxf(m2a, m2b);
                judge = ((__ballot(m1 < 0.0f) | __ballot(m2 < 0.0f)) != 0ull);
            }

            if (judge) {
                // ---- Gauss-Seidel sweep (ascending j, violators only) ----
                uint64_t rem_lo = ~0ull, rem_hi = ~0ull;
                while (true) {
                    uint64_t m1b_ = __ballot((s_lo > a_lo) || (s_lo < -a_lo)) & rem_lo;
                    uint64_t m2b_ = __ballot((s_hi > a_hi) || (s_hi < -a_hi)) & rem_hi;
                    int j;
                    if (m1b_) {
                        int jl = (int)__ffsll((unsigned long long)m1b_) - 1;
                        j = jl;
                        rem_lo = (jl == 63) ? 0ull : (~0ull << (jl + 1));
                    } else if (m2b_) {
                        int jh = (int)__ffsll((unsigned long long)m2b_) - 1;
                        j = 64 + jh;
                        rem_lo = 0ull;
                        rem_hi = (jh == 63) ? 0ull : (~0ull << (jh + 1));
                    } else {
                        break;
                    }
                    float dl2 = (s_lo > a_lo) ? (a_lo - s_lo) * rvd_lo
                               : ((s_lo < -a_lo) ? (-a_lo - s_lo) * rvd_lo : 0.0f);
                    float dh2 = (s_hi > a_hi) ? (a_hi - s_hi) * rvd_hi
                               : ((s_hi < -a_hi) ? (-a_hi - s_hi) * rvd_hi : 0.0f);
                    float srcv = (j < 64) ? dl2 : dh2;
                    float dj = lane_bcast(srcv, j & 63);
                    if (lane == (j & 63)) {
                        if (j < 64) h_lo += dj; else h_hi += dj;
                    }
                    float2 vj = vpair[(j << 6) + (lane ^ ((j & 3) << 2))];
                    s_lo = fmaf(vj.x, dj, s_lo);
                    s_hi = fmaf(vj.y, dj, s_hi);
                }
            } else {
                // ---- bisection between pi_bar (s=0) and adj (s), s-space ----
                float hin_lo = tgt_lo, hin_hi = tgt_hi;
                float sin_lo = 0.0f, sin_hi = 0.0f;
                float hout_lo = h_lo, hout_hi = h_hi;
                float sout_lo = s_lo, sout_hi = s_hi;
                float hm_lo = 0.0f, hm_hi = 0.0f;
#pragma unroll
                for (int it = 0; it < 10; ++it) {
                    hm_lo = hin_lo + (hout_lo - hin_lo) * 0.5f;
                    hm_hi = hin_hi + (hout_hi - hin_hi) * 0.5f;
                    float sm_lo = sin_lo + (sout_lo - sin_lo) * 0.5f;
                    float sm_hi = sin_hi + (sout_hi - sin_hi) * 0.5f;
                    bool pl = (sm_lo <= aeps_lo) && (sm_lo >= -aeps_lo);
                    bool ph = (sm_hi <= aeps_hi) && (sm_hi >= -aeps_hi);
                    bool inside = (__ballot(pl && ph) == ~0ull);
                    if (inside) {
                        hin_lo = hm_lo; hin_hi = hm_hi;
                        sin_lo = sm_lo; sin_hi = sm_hi;
                    } else {
                        hout_lo = hm_lo; hout_hi = hm_hi;
                        sout_lo = sm_lo; sout_hi = sm_hi;
                    }
                }
                h_lo = hm_lo;
                h_hi = hm_hi;
            }
        }
        // else: no violators -> judge=1, sweep is a no-op, h unchanged

        out[rlo * T * B + t * B + b] = h_lo;
        out[rhi * T * B + t * B + b] = h_hi;
    }

    out[D * T * B + rlo * B + b] = h_lo;
    out[D * T * B + rhi * B + b] = h_hi;
}

extern "C" void kernel_launch(void* const* d_in, const int* in_sizes, int n_in,
                              void* d_out, int out_size, void* d_ws, size_t ws_size,
                              hipStream_t stream) {
    const float* input   = (const float*)d_in[0];
    const float* target  = (const float*)d_in[1];
    const float* returns = (const float*)d_in[2];
    // d_in[3] = hidden (unused by the reference)
    const float* W = (const float*)d_in[4];
    const float* b = (const float*)d_in[5];
    float* out = (float*)d_out;

    float* vT   = (float*)d_ws;            // 16384 floats
    float* vd   = vT + D * D;              // 128 floats
    float* absb = vd + D;                  // 128 floats

    prep_kernel<<<D, 64, 0, stream>>>(W, b, vT, vd, absb);
    rnn_kernel<<<B / 2, 128, 0, stream>>>(input, target, returns, vT, vd, absb, out);
}

// Round 2
// 249.301 us; speedup vs baseline: 1.1167x; 1.1167x over previous
//
#include <hip/hip_runtime.h>
#include <cstdint>

#define D 128
#define T 64
#define B 512
#define EPSF 1e-5f

// wave-uniform lane broadcast via v_readlane (no LDS/ds_bpermute)
__device__ __forceinline__ float lane_bcast(float x, int l) {
    return __int_as_float(__builtin_amdgcn_readlane(__float_as_int(x), l));
}

// ---------------------------------------------------------------------------
// prep: vT[k*D+i] = v[i][k] = W[i][k]/max(norm_i,1e-12); vd[i]=v[i][i]; absb=|b|
// ---------------------------------------------------------------------------
__global__ __launch_bounds__(64) void prep_kernel(const float* __restrict__ W,
                                                  const float* __restrict__ b,
                                                  float* __restrict__ vT,
                                                  float* __restrict__ vd,
                                                  float* __restrict__ absb) {
    const int i = blockIdx.x;
    const int l = threadIdx.x;
    float w0 = W[i * D + l];
    float w1 = W[i * D + l + 64];
    float p = w0 * w0 + w1 * w1;
#pragma unroll
    for (int off = 32; off; off >>= 1) p += __shfl_xor(p, off);
    float norm = sqrtf(p);
    float scale = norm > 1e-12f ? norm : 1e-12f;
    float v0 = w0 / scale;
    float v1 = w1 / scale;
    vT[l * D + i] = v0;
    vT[(l + 64) * D + i] = v1;
    if (i < 64) {
        if (l == i) vd[i] = v0;
    } else {
        if (l == i - 64) vd[i] = v1;
    }
    if (i == 0) {
        absb[l] = fabsf(b[l]);
        absb[l + 64] = fabsf(b[l + 64]);
    }
}

// ---------------------------------------------------------------------------
// main RNN kernel. One wave per batch column; lane owns rows (lane, lane+64).
// Waves are fully independent after init: NO barriers in the t-loop (a
// __syncthreads here forces vmcnt(0) drain of the out-stores every step —
// measured −62% in round 1).
//
// Two LDS copies of v (129 KB total; grid = 256 blocks = 1 block/CU on a
// 160 KB/CU chip, so the extra LDS costs nothing):
//   vsh [k*128 + (i ^ ((k&7)<<2))] = v[i][k]   column layout: sweep/probe row
//                                              reads + judge b128 column scans
//                                              (verbatim round-0 correction)
//   vrow[i*128 + (k ^ ((i&7)<<2))] = v[i][k]   row layout: matvec ds_read_b128
//                                              of each lane's own rows
// x is staged per-wave in xsh[w] (wave-private: ds_write -> lgkm RAW wait,
// no barrier needed). Matvec accumulation order (k ascending, single
// accumulator) is identical to round-0 -> bit-identical s.
// ---------------------------------------------------------------------------
__global__ __launch_bounds__(128) void rnn_kernel(const float* __restrict__ input,
                                                  const float* __restrict__ target,
                                                  const float* __restrict__ returns,
                                                  const float* __restrict__ vTg,
                                                  const float* __restrict__ vdg,
                                                  const float* __restrict__ absbg,
                                                  float* __restrict__ out) {
    __shared__ __align__(16) float vsh[D * D];    // 64 KB (correction)
    __shared__ __align__(16) float vrow[D * D];   // 64 KB (matvec)
    __shared__ __align__(16) float xsh[2][D];     // 1 KB  (per-wave x stage)

    const int tid = threadIdx.x;
    // ---- build vsh (swizzled column layout) from plain vT ----
    {
        const float4* src = (const float4*)vTg;
        float4* dst = (float4*)vsh;
#pragma unroll
        for (int c = 0; c < 32; ++c) {
            int f = c * 128 + tid;          // source float4 index
            int k = f >> 5;                 // row k of vT (column of v)
            int i = (f & 31) << 2;          // starting i of this float4
            int ck = (k & 7) << 2;
            int d4 = k * 32 + (((i ^ ck)) >> 2);
            dst[d4] = src[f];
        }
    }
    // ---- build vrow (swizzled row layout) from plain vT ----
#pragma unroll
    for (int c = 0; c < 32; ++c) {
        int f = c * 128 + tid;              // dest float4 index
        int i = f >> 5;                     // row of v
        int k0 = (f & 31) << 2;
        float4 val;
        val.x = vTg[k0 * D + i];
        val.y = vTg[(k0 + 1) * D + i];
        val.z = vTg[(k0 + 2) * D + i];
        val.w = vTg[(k0 + 3) * D + i];
        *(float4*)&vrow[i * D + (k0 ^ ((i & 7) << 2))] = val;
    }
    __syncthreads();   // once, outside the t-loop

    const int w = tid >> 6;
    const int lane = tid & 63;
    const int b = blockIdx.x * 2 + w;
    const int rlo = lane, rhi = lane + 64;

    const float tgt_lo = target[rlo], tgt_hi = target[rhi];
    const float a_lo = absbg[rlo], a_hi = absbg[rhi];
    const float aeps_lo = a_lo + EPSF, aeps_hi = a_hi + EPSF;
    const float vd_lo = vdg[rlo], vd_hi = vdg[rhi];
    const float rvd_lo = 1.0f / vd_lo, rvd_hi = 1.0f / vd_hi;

    // matvec row pointers: lane's own rows, XOR-swizzled b128 reads
    const float* vr_lo = &vrow[rlo * D];
    const float* vr_hi = &vrow[rhi * D];
    const int swr = (rlo & 7) << 2;         // (rhi&7)==(rlo&7)
    float* xw = xsh[w];

    // parallel-judge column bases: candidate j=lane reads float4 at
    // Abase[c] + 32*a  (logical i0 = a*32 + c*4); candidate lane+64 at +8192
    const int cj = (lane & 7) << 2;
    int Abase[8];
#pragma unroll
    for (int c = 0; c < 8; ++c) Abase[c] = lane * 128 + ((c << 2) ^ cj);

    float h_lo = input[rlo * T * B + b];
    float h_hi = input[rhi * T * B + b];
    out[rlo * T * B + b] = h_lo;
    out[rhi * T * B + b] = h_hi;

    float r_lo = returns[rlo * T * B + b];
    float r_hi = returns[rhi * T * B + b];

    for (int t = 1; t < T; ++t) {
        // ---- adj = h*(1+r)/(1 + sum(h*r)) ----
        float num_lo = h_lo * (1.0f + r_lo);
        float num_hi = h_hi * (1.0f + r_hi);
        float p = h_lo * r_lo + h_hi * r_hi;
#pragma unroll
        for (int off = 32; off; off >>= 1) p += __shfl_xor(p, off);
        float den = 1.0f + p;
        float adj_lo = num_lo / den;
        float adj_hi = num_hi / den;

        if (t < T - 1) {
            r_lo = returns[rlo * T * B + t * B + b];
            r_hi = returns[rhi * T * B + t * B + b];
        }

        // ---- stage x = adj - pi_bar in wave-private LDS (no barrier) ----
        float x_lo = adj_lo - tgt_lo;
        float x_hi = adj_hi - tgt_hi;
        xw[rlo] = x_lo;
        xw[rhi] = x_hi;
        h_lo = adj_lo;
        h_hi = adj_hi;

        // ---- matvec: s = v @ x, b128 row reads, k ascending (bit-identical
        //      order to round-0's scalar loop) ----
        float s_lo = 0.0f, s_hi = 0.0f;
#pragma unroll
        for (int k4 = 0; k4 < D; k4 += 4) {
            float4 a = *(const float4*)&vr_lo[k4 ^ swr];
            float4 c = *(const float4*)&vr_hi[k4 ^ swr];
            float4 x = *(const float4*)&xw[k4];
            s_lo = fmaf(a.x, x.x, s_lo);
            s_lo = fmaf(a.y, x.y, s_lo);
            s_lo = fmaf(a.z, x.z, s_lo);
            s_lo = fmaf(a.w, x.w, s_lo);
            s_hi = fmaf(c.x, x.x, s_hi);
            s_hi = fmaf(c.y, x.y, s_hi);
            s_hi = fmaf(c.z, x.z, s_hi);
            s_hi = fmaf(c.w, x.w, s_hi);
        }

        // ================= correction (verbatim round-0) ===================
        bool viol_lo = (s_lo > a_lo) || (s_lo < -a_lo);
        bool viol_hi = (s_hi > a_hi) || (s_hi < -a_hi);
        uint64_t mlo = __ballot(viol_lo);
        uint64_t mhi = __ballot(viol_hi);

        if ((mlo | mhi) != 0ull) {
            // per-lane deltas (reference lam formulas, IEEE div)
            float dl = 0.0f, dh = 0.0f;
            if (s_lo > a_lo) dl = (a_lo - s_lo) / vd_lo;
            else if (s_lo < -a_lo) dl = (-a_lo - s_lo) / vd_lo;
            if (s_hi > a_hi) dh = (a_hi - s_hi) / vd_hi;
            else if (s_hi < -a_hi) dh = (-a_hi - s_hi) / vd_hi;

            int V = __popcll(mlo) + __popcll(mhi);
            bool judge;

            if (V <= 8) {
                // q0: all strictly inside a+eps and (V<64 so) a zero-delta
                // column exists
                bool in_lo = (s_lo < aeps_lo) && (s_lo > -aeps_lo);
                bool in_hi = (s_hi < aeps_hi) && (s_hi > -aeps_hi);
                judge = (__ballot(in_lo && in_hi) == ~0ull);
                if (!judge) {
                    uint64_t t_mlo = mlo, t_mhi = mhi;
                    while (t_mlo | t_mhi) {
                        int j;
                        float dj;
                        if (t_mlo) {
                            int jl = (int)__ffsll((unsigned long long)t_mlo) - 1;
                            t_mlo &= t_mlo - 1;
                            j = jl;
                            dj = lane_bcast(dl, jl);
                        } else {
                            int jh = (int)__ffsll((unsigned long long)t_mhi) - 1;
                            t_mhi &= t_mhi - 1;
                            j = 64 + jh;
                            dj = lane_bcast(dh, jh);
                        }
                        int cjj = (j & 7) << 2;
                        int base = j * 128 + (rlo ^ cjj);
                        float n_lo = fmaf(vsh[base], dj, s_lo);
                        float n_hi = fmaf(vsh[base + 64], dj, s_hi);
                        bool pl = (n_lo < aeps_lo) && (n_lo > -aeps_lo);
                        bool ph = (n_hi < aeps_hi) && (n_hi > -aeps_hi);
                        if (__ballot(pl && ph) == ~0ull) { judge = true; break; }
                    }
                }
            } else {
                // ---- parallel judge: lane tests candidates j=lane, lane+64.
                // Covers d=0 candidates (q0) uniformly.
                float m1 = -1.0f, m2 = -1.0f;   // only the sign of max matters
#pragma unroll
                for (int a = 0; a < 4; ++a) {
#pragma unroll
                    for (int c = 0; c < 8; ++c) {
                        const int i0 = a * 32 + c * 4;
                        const float* p1 = &vsh[Abase[c] + 32 * a];
                        float4 c1 = *(const float4*)p1;
                        float4 c2 = *(const float4*)(p1 + 8192);
#pragma unroll
                        for (int e = 0; e < 4; ++e) {
                            const int i = i0 + e;
                            float sv = (i < 64) ? lane_bcast(s_lo, i)
                                                : lane_bcast(s_hi, i - 64);
                            float ae = (i < 64) ? lane_bcast(aeps_lo, i)
                                                : lane_bcast(aeps_hi, i - 64);
                            float f1 = ((const float*)&c1)[e];
                            float f2 = ((const float*)&c2)[e];
                            m1 = fmaxf(m1, fabsf(fmaf(f1, dl, sv)) - ae);
                            m2 = fmaxf(m2, fabsf(fmaf(f2, dh, sv)) - ae);
                        }
                    }
                }
                judge = ((__ballot(m1 < 0.0f) | __ballot(m2 < 0.0f)) != 0ull);
            }

            if (judge) {
                // ---- Gauss-Seidel sweep (ascending j, violators only) ----
                uint64_t rem_lo = ~0ull, rem_hi = ~0ull;
                while (true) {
                    uint64_t m1b = __ballot((s_lo > a_lo) || (s_lo < -a_lo)) & rem_lo;
                    uint64_t m2b = __ballot((s_hi > a_hi) || (s_hi < -a_hi)) & rem_hi;
                    int j;
                    if (m1b) {
                        int jl = (int)__ffsll((unsigned long long)m1b) - 1;
                        j = jl;
                        rem_lo = (jl == 63) ? 0ull : (~0ull << (jl + 1));
                    } else if (m2b) {
                        int jh = (int)__ffsll((unsigned long long)m2b) - 1;
                        j = 64 + jh;
                        rem_lo = 0ull;
                        rem_hi = (jh == 63) ? 0ull : (~0ull << (jh + 1));
                    } else {
                        break;
                    }
                    float dl2 = (s_lo > a_lo) ? (a_lo - s_lo) * rvd_lo
                               : ((s_lo < -a_lo) ? (-a_lo - s_lo) * rvd_lo : 0.0f);
                    float dh2 = (s_hi > a_hi) ? (a_hi - s_hi) * rvd_hi
                               : ((s_hi < -a_hi) ? (-a_hi - s_hi) * rvd_hi : 0.0f);
                    float srcv = (j < 64) ? dl2 : dh2;
                    float dj = lane_bcast(srcv, j & 63);
                    if (lane == (j & 63)) {
                        if (j < 64) h_lo += dj; else h_hi += dj;
                    }
                    int cjj = (j & 7) << 2;
                    int base = j * 128 + (rlo ^ cjj);
                    s_lo = fmaf(vsh[base], dj, s_lo);
                    s_hi = fmaf(vsh[base + 64], dj, s_hi);
                }
            } else {
                // ---- bisection between pi_bar (s=0) and adj (s), s-space ----
                float hin_lo = tgt_lo, hin_hi = tgt_hi;
                float sin_lo = 0.0f, sin_hi = 0.0f;
                float hout_lo = h_lo, hout_hi = h_hi;
                float sout_lo = s_lo, sout_hi = s_hi;
                float hm_lo = 0.0f, hm_hi = 0.0f;
#pragma unroll
                for (int it = 0; it < 10; ++it) {
                    hm_lo = hin_lo + (hout_lo - hin_lo) * 0.5f;
                    hm_hi = hin_hi + (hout_hi - hin_hi) * 0.5f;
                    float sm_lo = sin_lo + (sout_lo - sin_lo) * 0.5f;
                    float sm_hi = sin_hi + (sout_hi - sin_hi) * 0.5f;
                    bool pl = (sm_lo <= aeps_lo) && (sm_lo >= -aeps_lo);
                    bool ph = (sm_hi <= aeps_hi) && (sm_hi >= -aeps_hi);
                    bool inside = (__ballot(pl && ph) == ~0ull);
                    if (inside) {
                        hin_lo = hm_lo; hin_hi = hm_hi;
                        sin_lo = sm_lo; sin_hi = sm_hi;
                    } else {
                        hout_lo = hm_lo; hout_hi = hm_hi;
                        sout_lo = sm_lo; sout_hi = sm_hi;
                    }
                }
                h_lo = hm_lo;
                h_hi = hm_hi;
            }
        }
        // else: no violators -> judge=1, sweep is a no-op, h unchanged

        out[rlo * T * B + t * B + b] = h_lo;
        out[rhi * T * B + t * B + b] = h_hi;
    }

    out[D * T * B + rlo * B + b] = h_lo;
    out[D * T * B + rhi * B + b] = h_hi;
}

extern "C" void kernel_launch(void* const* d_in, const int* in_sizes, int n_in,
                              void* d_out, int out_size, void* d_ws, size_t ws_size,
                              hipStream_t stream) {
    const float* input   = (const float*)d_in[0];
    const float* target  = (const float*)d_in[1];
    const float* returns = (const float*)d_in[2];
    // d_in[3] = hidden (unused by the reference)
    const float* W = (const float*)d_in[4];
    const float* b = (const float*)d_in[5];
    float* out = (float*)d_out;

    float* vT   = (float*)d_ws;            // 16384 floats
    float* vd   = vT + D * D;              // 128 floats
    float* absb = vd + D;                  // 128 floats

    prep_kernel<<<D, 64, 0, stream>>>(W, b, vT, vd, absb);
    rnn_kernel<<<B / 2, 128, 0, stream>>>(input, target, returns, vT, vd, absb, out);
}

// Round 3
// 216.958 us; speedup vs baseline: 1.2832x; 1.1491x over previous
//
#include <hip/hip_runtime.h>
#include <cstdint>

#define D 128
#define T 64
#define B 512
#define EPSF 1e-5f

// wave-uniform lane broadcast via v_readlane (no LDS/ds_bpermute)
__device__ __forceinline__ float lane_bcast(float x, int l) {
    return __int_as_float(__builtin_amdgcn_readlane(__float_as_int(x), l));
}

// ---------------------------------------------------------------------------
// prep: vT[k*D+i] = v[i][k] = W[i][k]/max(norm_i,1e-12); vd[i]=v[i][i]; absb=|b|
// ---------------------------------------------------------------------------
__global__ __launch_bounds__(64) void prep_kernel(const float* __restrict__ W,
                                                  const float* __restrict__ b,
                                                  float* __restrict__ vT,
                                                  float* __restrict__ vd,
                                                  float* __restrict__ absb) {
    const int i = blockIdx.x;
    const int l = threadIdx.x;
    float w0 = W[i * D + l];
    float w1 = W[i * D + l + 64];
    float p = w0 * w0 + w1 * w1;
#pragma unroll
    for (int off = 32; off; off >>= 1) p += __shfl_xor(p, off);
    float norm = sqrtf(p);
    float scale = norm > 1e-12f ? norm : 1e-12f;
    float v0 = w0 / scale;
    float v1 = w1 / scale;
    vT[l * D + i] = v0;
    vT[(l + 64) * D + i] = v1;
    if (i < 64) {
        if (l == i) vd[i] = v0;
    } else {
        if (l == i - 64) vd[i] = v1;
    }
    if (i == 0) {
        absb[l] = fabsf(b[l]);
        absb[l + 64] = fabsf(b[l + 64]);
    }
}

// ---------------------------------------------------------------------------
// main RNN kernel. One wave per batch column; lane owns rows (lane, lane+64).
// NO barriers in the t-loop (round-1 measured −62% from per-step vmcnt(0)
// drains). Round-2 lesson: any LDS-based matvec streams the whole 64KB
// matrix per wave per step (~1024 cy/step/CU of raw LDS BW) — so the matvec
// now reads v from REGISTERS: lane holds rows (lane, lane+64) in vl[]/vh[]
// (256 VGPRs, statically indexed; occupancy is grid-pinned at 2 waves/CU so
// the registers are free). x is broadcast via v_readlane, k-ascending single
// accumulator -> bit-identical s to the 144.8us round-0 kernel.
//
// vsh (swizzled column layout) stays in LDS for the correction phase only
// (sweep/probe/judge need runtime-j column access; register arrays can't be
// runtime-indexed without scratch spill):
//   vsh[k*128 + (i ^ ((k&7)<<2))] = v[i][k]
//  - row reads (probe/sweep; fixed k, i=lane): 2-way bank alias = free
//  - column reads (parallel judge; fixed j=lane, i contiguous x4): b128,
//    8 requests/bank = structural minimum
// ---------------------------------------------------------------------------
__global__ __launch_bounds__(128, 1) void rnn_kernel(const float* __restrict__ input,
                                                     const float* __restrict__ target,
                                                     const float* __restrict__ returns,
                                                     const float* __restrict__ vTg,
                                                     const float* __restrict__ vdg,
                                                     const float* __restrict__ absbg,
                                                     float* __restrict__ out) {
    __shared__ float vsh[D * D];   // exactly 64 KB

    const int tid = threadIdx.x;
    // cooperative swizzled load of vT (plain layout in ws -> swizzled LDS)
    {
        const float4* src = (const float4*)vTg;
        float4* dst = (float4*)vsh;
#pragma unroll
        for (int c = 0; c < 32; ++c) {
            int f = c * 128 + tid;          // source float4 index
            int k = f >> 5;                 // row k of vT
            int i = (f & 31) << 2;          // starting i of this float4
            int ck = (k & 7) << 2;
            int d4 = k * 32 + (((i ^ ck)) >> 2);
            dst[d4] = src[f];
        }
    }
    __syncthreads();

    const int w = tid >> 6;
    const int lane = tid & 63;
    const int b = blockIdx.x * 2 + w;
    const int rlo = lane, rhi = lane + 64;

    const float tgt_lo = target[rlo], tgt_hi = target[rhi];
    const float a_lo = absbg[rlo], a_hi = absbg[rhi];
    const float aeps_lo = a_lo + EPSF, aeps_hi = a_hi + EPSF;
    const float vd_lo = vdg[rlo], vd_hi = vdg[rhi];
    const float rvd_lo = 1.0f / vd_lo, rvd_hi = 1.0f / vd_hi;

    // row-read xor bases: vsh[k*128 + ax[k&7]] (+64 for hi row)
    int ax[8];
#pragma unroll
    for (int c = 0; c < 8; ++c) ax[c] = rlo ^ (c << 2);

    // ---- register-resident v rows for the matvec (one-time LDS read;
    //      static indices only -> stays in VGPRs) ----
    float vl[D], vh[D];
#pragma unroll
    for (int k = 0; k < D; ++k) {
        int base = k * 128 + ax[k & 7];
        vl[k] = vsh[base];
        vh[k] = vsh[base + 64];
    }

    // parallel-judge column bases: candidate j=lane reads float4 at
    // Abase[c] + 32*a  (logical i0 = a*32 + c*4); candidate lane+64 at +8192
    const int cj = (lane & 7) << 2;
    int Abase[8];
#pragma unroll
    for (int c = 0; c < 8; ++c) Abase[c] = lane * 128 + ((c << 2) ^ cj);

    float h_lo = input[rlo * T * B + b];
    float h_hi = input[rhi * T * B + b];
    out[rlo * T * B + b] = h_lo;
    out[rhi * T * B + b] = h_hi;

    float r_lo = returns[rlo * T * B + b];
    float r_hi = returns[rhi * T * B + b];

    for (int t = 1; t < T; ++t) {
        // ---- adj = h*(1+r)/(1 + sum(h*r)) ----
        float num_lo = h_lo * (1.0f + r_lo);
        float num_hi = h_hi * (1.0f + r_hi);
        float p = h_lo * r_lo + h_hi * r_hi;
#pragma unroll
        for (int off = 32; off; off >>= 1) p += __shfl_xor(p, off);
        float den = 1.0f + p;
        float adj_lo = num_lo / den;
        float adj_hi = num_hi / den;

        if (t < T - 1) {
            r_lo = returns[rlo * T * B + t * B + b];
            r_hi = returns[rhi * T * B + t * B + b];
        }

        const float x_lo = adj_lo - tgt_lo;
        const float x_hi = adj_hi - tgt_hi;

        // ---- s = v @ (adj - pi_bar): readlane broadcast + register v.
        //      k ascending, single accumulator per row -> bit-identical to
        //      round-0's LDS version. Zero LDS traffic. ----
        float s_lo = 0.0f, s_hi = 0.0f;
#pragma unroll
        for (int k = 0; k < 64; ++k) {
            float xb = lane_bcast(x_lo, k);
            s_lo = fmaf(vl[k], xb, s_lo);
            s_hi = fmaf(vh[k], xb, s_hi);
        }
#pragma unroll
        for (int k = 0; k < 64; ++k) {
            float xb = lane_bcast(x_hi, k);
            s_lo = fmaf(vl[64 + k], xb, s_lo);
            s_hi = fmaf(vh[64 + k], xb, s_hi);
        }

        h_lo = adj_lo;
        h_hi = adj_hi;

        // ================= correction (verbatim round-0) ===================
        bool viol_lo = (s_lo > a_lo) || (s_lo < -a_lo);
        bool viol_hi = (s_hi > a_hi) || (s_hi < -a_hi);
        uint64_t mlo = __ballot(viol_lo);
        uint64_t mhi = __ballot(viol_hi);

        if ((mlo | mhi) != 0ull) {
            // per-lane deltas (reference lam formulas, IEEE div)
            float dl = 0.0f, dh = 0.0f;
            if (s_lo > a_lo) dl = (a_lo - s_lo) / vd_lo;
            else if (s_lo < -a_lo) dl = (-a_lo - s_lo) / vd_lo;
            if (s_hi > a_hi) dh = (a_hi - s_hi) / vd_hi;
            else if (s_hi < -a_hi) dh = (-a_hi - s_hi) / vd_hi;

            int V = __popcll(mlo) + __popcll(mhi);
            bool judge;

            if (V <= 8) {
                // q0: all strictly inside a+eps and (V<64 so) a zero-delta
                // column exists
                bool in_lo = (s_lo < aeps_lo) && (s_lo > -aeps_lo);
                bool in_hi = (s_hi < aeps_hi) && (s_hi > -aeps_hi);
                judge = (__ballot(in_lo && in_hi) == ~0ull);
                if (!judge) {
                    uint64_t t_mlo = mlo, t_mhi = mhi;
                    while (t_mlo | t_mhi) {
                        int j;
                        float dj;
                        if (t_mlo) {
                            int jl = (int)__ffsll((unsigned long long)t_mlo) - 1;
                            t_mlo &= t_mlo - 1;
                            j = jl;
                            dj = lane_bcast(dl, jl);
                        } else {
                            int jh = (int)__ffsll((unsigned long long)t_mhi) - 1;
                            t_mhi &= t_mhi - 1;
                            j = 64 + jh;
                            dj = lane_bcast(dh, jh);
                        }
                        int cjj = (j & 7) << 2;
                        int base = j * 128 + (rlo ^ cjj);
                        float n_lo = fmaf(vsh[base], dj, s_lo);
                        float n_hi = fmaf(vsh[base + 64], dj, s_hi);
                        bool pl = (n_lo < aeps_lo) && (n_lo > -aeps_lo);
                        bool ph = (n_hi < aeps_hi) && (n_hi > -aeps_hi);
                        if (__ballot(pl && ph) == ~0ull) { judge = true; break; }
                    }
                }
            } else {
                // ---- parallel judge: lane tests candidates j=lane, lane+64.
                // Covers d=0 candidates (q0) uniformly.
                float m1 = -1.0f, m2 = -1.0f;   // only the sign of max matters
#pragma unroll
                for (int a = 0; a < 4; ++a) {
#pragma unroll
                    for (int c = 0; c < 8; ++c) {
                        const int i0 = a * 32 + c * 4;
                        const float* p1 = &vsh[Abase[c] + 32 * a];
                        float4 c1 = *(const float4*)p1;
                        float4 c2 = *(const float4*)(p1 + 8192);
#pragma unroll
                        for (int e = 0; e < 4; ++e) {
                            const int i = i0 + e;
                            float sv = (i < 64) ? lane_bcast(s_lo, i)
                                                : lane_bcast(s_hi, i - 64);
                            float ae = (i < 64) ? lane_bcast(aeps_lo, i)
                                                : lane_bcast(aeps_hi, i - 64);
                            float f1 = ((const float*)&c1)[e];
                            float f2 = ((const float*)&c2)[e];
                            m1 = fmaxf(m1, fabsf(fmaf(f1, dl, sv)) - ae);
                            m2 = fmaxf(m2, fabsf(fmaf(f2, dh, sv)) - ae);
                        }
                    }
                }
                judge = ((__ballot(m1 < 0.0f) | __ballot(m2 < 0.0f)) != 0ull);
            }

            if (judge) {
                // ---- Gauss-Seidel sweep (ascending j, violators only) ----
                uint64_t rem_lo = ~0ull, rem_hi = ~0ull;
                while (true) {
                    uint64_t m1b = __ballot((s_lo > a_lo) || (s_lo < -a_lo)) & rem_lo;
                    uint64_t m2b = __ballot((s_hi > a_hi) || (s_hi < -a_hi)) & rem_hi;
                    int j;
                    if (m1b) {
                        int jl = (int)__ffsll((unsigned long long)m1b) - 1;
                        j = jl;
                        rem_lo = (jl == 63) ? 0ull : (~0ull << (jl + 1));
                    } else if (m2b) {
                        int jh = (int)__ffsll((unsigned long long)m2b) - 1;
                        j = 64 + jh;
                        rem_lo = 0ull;
                        rem_hi = (jh == 63) ? 0ull : (~0ull << (jh + 1));
                    } else {
                        break;
                    }
                    float dl2 = (s_lo > a_lo) ? (a_lo - s_lo) * rvd_lo
                               : ((s_lo < -a_lo) ? (-a_lo - s_lo) * rvd_lo : 0.0f);
                    float dh2 = (s_hi > a_hi) ? (a_hi - s_hi) * rvd_hi
                               : ((s_hi < -a_hi) ? (-a_hi - s_hi) * rvd_hi : 0.0f);
                    float srcv = (j < 64) ? dl2 : dh2;
                    float dj = lane_bcast(srcv, j & 63);
                    if (lane == (j & 63)) {
                        if (j < 64) h_lo += dj; else h_hi += dj;
                    }
                    int cjj = (j & 7) << 2;
                    int base = j * 128 + (rlo ^ cjj);
                    s_lo = fmaf(vsh[base], dj, s_lo);
                    s_hi = fmaf(vsh[base + 64], dj, s_hi);
                }
            } else {
                // ---- bisection between pi_bar (s=0) and adj (s), s-space ----
                float hin_lo = tgt_lo, hin_hi = tgt_hi;
                float sin_lo = 0.0f, sin_hi = 0.0f;
                float hout_lo = h_lo, hout_hi = h_hi;
                float sout_lo = s_lo, sout_hi = s_hi;
                float hm_lo = 0.0f, hm_hi = 0.0f;
#pragma unroll
                for (int it = 0; it < 10; ++it) {
                    hm_lo = hin_lo + (hout_lo - hin_lo) * 0.5f;
                    hm_hi = hin_hi + (hout_hi - hin_hi) * 0.5f;
                    float sm_lo = sin_lo + (sout_lo - sin_lo) * 0.5f;
                    float sm_hi = sin_hi + (sout_hi - sin_hi) * 0.5f;
                    bool pl = (sm_lo <= aeps_lo) && (sm_lo >= -aeps_lo);
                    bool ph = (sm_hi <= aeps_hi) && (sm_hi >= -aeps_hi);
                    bool inside = (__ballot(pl && ph) == ~0ull);
                    if (inside) {
                        hin_lo = hm_lo; hin_hi = hm_hi;
                        sin_lo = sm_lo; sin_hi = sm_hi;
                    } else {
                        hout_lo = hm_lo; hout_hi = hm_hi;
                        sout_lo = sm_lo; sout_hi = sm_hi;
                    }
                }
                h_lo = hm_lo;
                h_hi = hm_hi;
            }
        }
        // else: no violators -> judge=1, sweep is a no-op, h unchanged

        out[rlo * T * B + t * B + b] = h_lo;
        out[rhi * T * B + t * B + b] = h_hi;
    }

    out[D * T * B + rlo * B + b] = h_lo;
    out[D * T * B + rhi * B + b] = h_hi;
}

extern "C" void kernel_launch(void* const* d_in, const int* in_sizes, int n_in,
                              void* d_out, int out_size, void* d_ws, size_t ws_size,
                              hipStream_t stream) {
    const float* input   = (const float*)d_in[0];
    const float* target  = (const float*)d_in[1];
    const float* returns = (const float*)d_in[2];
    // d_in[3] = hidden (unused by the reference)
    const float* W = (const float*)d_in[4];
    const float* b = (const float*)d_in[5];
    float* out = (float*)d_out;

    float* vT   = (float*)d_ws;            // 16384 floats
    float* vd   = vT + D * D;              // 128 floats
    float* absb = vd + D;                  // 128 floats

    prep_kernel<<<D, 64, 0, stream>>>(W, b, vT, vd, absb);
    rnn_kernel<<<B / 2, 128, 0, stream>>>(input, target, returns, vT, vd, absb, out);
}

// Round 4
// 215.445 us; speedup vs baseline: 1.2922x; 1.0070x over previous
//
#include <hip/hip_runtime.h>
#include <cstdint>

#define D 128
#define T 64
#define B 512
#define EPSF 1e-5f

// wave-uniform lane broadcast via v_readlane (no LDS/ds_bpermute)
__device__ __forceinline__ float lane_bcast(float x, int l) {
    return __int_as_float(__builtin_amdgcn_readlane(__float_as_int(x), l));
}

// ---------------------------------------------------------------------------
// prep: vT[k*D+i] = v[i][k] = W[i][k]/max(norm_i,1e-12); vd[i]=v[i][i]; absb=|b|
// ---------------------------------------------------------------------------
__global__ __launch_bounds__(64) void prep_kernel(const float* __restrict__ W,
                                                  const float* __restrict__ b,
                                                  float* __restrict__ vT,
                                                  float* __restrict__ vd,
                                                  float* __restrict__ absb) {
    const int i = blockIdx.x;
    const int l = threadIdx.x;
    float w0 = W[i * D + l];
    float w1 = W[i * D + l + 64];
    float p = w0 * w0 + w1 * w1;
#pragma unroll
    for (int off = 32; off; off >>= 1) p += __shfl_xor(p, off);
    float norm = sqrtf(p);
    float scale = norm > 1e-12f ? norm : 1e-12f;
    float v0 = w0 / scale;
    float v1 = w1 / scale;
    vT[l * D + i] = v0;
    vT[(l + 64) * D + i] = v1;
    if (i < 64) {
        if (l == i) vd[i] = v0;
    } else {
        if (l == i - 64) vd[i] = v1;
    }
    if (i == 0) {
        absb[l] = fabsf(b[l]);
        absb[l + 64] = fabsf(b[l + 64]);
    }
}

// ---------------------------------------------------------------------------
// main RNN kernel. One wave per batch column; lane owns rows (lane, lane+64).
// NO barriers in the t-loop (round-1: per-step vmcnt(0) drains cost −62%).
//
// Round-3 lesson (VGPR_Count stayed 156, conflicts byte-identical to round-0):
// a plain C array copy of v gets REMATERIALIZED back into per-step ds_reads.
// Those 256 scalar LDS reads/step are latency-bound (~120cy each, ~12 in
// flight at 156 VGPRs) — the dominant cost. Fix: pin each lane's two v-rows
// into AGPR-class registers via empty asm ("+a"). The asm result is opaque
// (cannot be rematerialized), AGPR class keeps arch-VGPR pressure flat, and
// at 2 waves/CU the unified 512-reg file has room (256 AGPR + ~156 VGPR).
// Matvec: zero LDS traffic, zero memory latency. Values and accumulation
// order unchanged -> bit-identical output.
//
// vsh (swizzled column layout) stays in LDS for the correction phase only
// (sweep/probe/judge need runtime-j column access):
//   vsh[k*128 + (i ^ ((k&7)<<2))] = v[i][k]
//  - row reads (probe/sweep; fixed k, i=lane): 2-way bank alias = free
//  - column reads (parallel judge, ~1% of steps per conflict counters):
//    b128, 8 requests/bank = structural minimum
// ---------------------------------------------------------------------------
__global__ __launch_bounds__(128, 1) void rnn_kernel(const float* __restrict__ input,
                                                     const float* __restrict__ target,
                                                     const float* __restrict__ returns,
                                                     const float* __restrict__ vTg,
                                                     const float* __restrict__ vdg,
                                                     const float* __restrict__ absbg,
                                                     float* __restrict__ out) {
    __shared__ float vsh[D * D];   // exactly 64 KB

    const int tid = threadIdx.x;
    // cooperative swizzled load of vT (plain layout in ws -> swizzled LDS)
    {
        const float4* src = (const float4*)vTg;
        float4* dst = (float4*)vsh;
#pragma unroll
        for (int c = 0; c < 32; ++c) {
            int f = c * 128 + tid;          // source float4 index
            int k = f >> 5;                 // row k of vT
            int i = (f & 31) << 2;          // starting i of this float4
            int ck = (k & 7) << 2;
            int d4 = k * 32 + (((i ^ ck)) >> 2);
            dst[d4] = src[f];
        }
    }
    __syncthreads();

    const int w = tid >> 6;
    const int lane = tid & 63;
    const int b = blockIdx.x * 2 + w;
    const int rlo = lane, rhi = lane + 64;

    const float tgt_lo = target[rlo], tgt_hi = target[rhi];
    const float a_lo = absbg[rlo], a_hi = absbg[rhi];
    const float aeps_lo = a_lo + EPSF, aeps_hi = a_hi + EPSF;
    const float vd_lo = vdg[rlo], vd_hi = vdg[rhi];
    const float rvd_lo = 1.0f / vd_lo, rvd_hi = 1.0f / vd_hi;

    // row-read xor bases: vsh[k*128 + ax[k&7]] (+64 for hi row)
    int ax[8];
#pragma unroll
    for (int c = 0; c < 8; ++c) ax[c] = rlo ^ (c << 2);

    // ---- register-resident v rows, PINNED in AGPRs (one-time LDS read;
    //      "+a" asm result is non-rematerializable -> stays resident) ----
    float vl[D], vh[D];
#pragma unroll
    for (int k = 0; k < D; ++k) {
        int base = k * 128 + ax[k & 7];
        vl[k] = vsh[base];
        vh[k] = vsh[base + 64];
        asm volatile("" : "+a"(vl[k]), "+a"(vh[k]));
    }

    // parallel-judge column bases: candidate j=lane reads float4 at
    // Abase[c] + 32*a  (logical i0 = a*32 + c*4); candidate lane+64 at +8192
    const int cj = (lane & 7) << 2;
    int Abase[8];
#pragma unroll
    for (int c = 0; c < 8; ++c) Abase[c] = lane * 128 + ((c << 2) ^ cj);

    float h_lo = input[rlo * T * B + b];
    float h_hi = input[rhi * T * B + b];
    out[rlo * T * B + b] = h_lo;
    out[rhi * T * B + b] = h_hi;

    float r_lo = returns[rlo * T * B + b];
    float r_hi = returns[rhi * T * B + b];

    for (int t = 1; t < T; ++t) {
        // ---- adj = h*(1+r)/(1 + sum(h*r)) ----
        float num_lo = h_lo * (1.0f + r_lo);
        float num_hi = h_hi * (1.0f + r_hi);
        float p = h_lo * r_lo + h_hi * r_hi;
#pragma unroll
        for (int off = 32; off; off >>= 1) p += __shfl_xor(p, off);
        float den = 1.0f + p;
        float adj_lo = num_lo / den;
        float adj_hi = num_hi / den;

        if (t < T - 1) {
            r_lo = returns[rlo * T * B + t * B + b];
            r_hi = returns[rhi * T * B + t * B + b];
        }

        const float x_lo = adj_lo - tgt_lo;
        const float x_hi = adj_hi - tgt_hi;

        // ---- s = v @ (adj - pi_bar): readlane broadcast + AGPR-resident v.
        //      k ascending, single accumulator per row -> bit-identical to
        //      round-0. Zero LDS traffic, zero memory latency. ----
        float s_lo = 0.0f, s_hi = 0.0f;
#pragma unroll
        for (int k = 0; k < 64; ++k) {
            float xb = lane_bcast(x_lo, k);
            s_lo = fmaf(vl[k], xb, s_lo);
            s_hi = fmaf(vh[k], xb, s_hi);
        }
#pragma unroll
        for (int k = 0; k < 64; ++k) {
            float xb = lane_bcast(x_hi, k);
            s_lo = fmaf(vl[64 + k], xb, s_lo);
            s_hi = fmaf(vh[64 + k], xb, s_hi);
        }

        h_lo = adj_lo;
        h_hi = adj_hi;

        // ================= correction (verbatim round-0) ===================
        bool viol_lo = (s_lo > a_lo) || (s_lo < -a_lo);
        bool viol_hi = (s_hi > a_hi) || (s_hi < -a_hi);
        uint64_t mlo = __ballot(viol_lo);
        uint64_t mhi = __ballot(viol_hi);

        if ((mlo | mhi) != 0ull) {
            // per-lane deltas (reference lam formulas, IEEE div)
            float dl = 0.0f, dh = 0.0f;
            if (s_lo > a_lo) dl = (a_lo - s_lo) / vd_lo;
            else if (s_lo < -a_lo) dl = (-a_lo - s_lo) / vd_lo;
            if (s_hi > a_hi) dh = (a_hi - s_hi) / vd_hi;
            else if (s_hi < -a_hi) dh = (-a_hi - s_hi) / vd_hi;

            int V = __popcll(mlo) + __popcll(mhi);
            bool judge;

            if (V <= 8) {
                // q0: all strictly inside a+eps and (V<64 so) a zero-delta
                // column exists
                bool in_lo = (s_lo < aeps_lo) && (s_lo > -aeps_lo);
                bool in_hi = (s_hi < aeps_hi) && (s_hi > -aeps_hi);
                judge = (__ballot(in_lo && in_hi) == ~0ull);
                if (!judge) {
                    uint64_t t_mlo = mlo, t_mhi = mhi;
                    while (t_mlo | t_mhi) {
                        int j;
                        float dj;
                        if (t_mlo) {
                            int jl = (int)__ffsll((unsigned long long)t_mlo) - 1;
                            t_mlo &= t_mlo - 1;
                            j = jl;
                            dj = lane_bcast(dl, jl);
                        } else {
                            int jh = (int)__ffsll((unsigned long long)t_mhi) - 1;
                            t_mhi &= t_mhi - 1;
                            j = 64 + jh;
                            dj = lane_bcast(dh, jh);
                        }
                        int cjj = (j & 7) << 2;
                        int base = j * 128 + (rlo ^ cjj);
                        float n_lo = fmaf(vsh[base], dj, s_lo);
                        float n_hi = fmaf(vsh[base + 64], dj, s_hi);
                        bool pl = (n_lo < aeps_lo) && (n_lo > -aeps_lo);
                        bool ph = (n_hi < aeps_hi) && (n_hi > -aeps_hi);
                        if (__ballot(pl && ph) == ~0ull) { judge = true; break; }
                    }
                }
            } else {
                // ---- parallel judge: lane tests candidates j=lane, lane+64.
                // Covers d=0 candidates (q0) uniformly.
                float m1 = -1.0f, m2 = -1.0f;   // only the sign of max matters
#pragma unroll
                for (int a = 0; a < 4; ++a) {
#pragma unroll
                    for (int c = 0; c < 8; ++c) {
                        const int i0 = a * 32 + c * 4;
                        const float* p1 = &vsh[Abase[c] + 32 * a];
                        float4 c1 = *(const float4*)p1;
                        float4 c2 = *(const float4*)(p1 + 8192);
#pragma unroll
                        for (int e = 0; e < 4; ++e) {
                            const int i = i0 + e;
                            float sv = (i < 64) ? lane_bcast(s_lo, i)
                                                : lane_bcast(s_hi, i - 64);
                            float ae = (i < 64) ? lane_bcast(aeps_lo, i)
                                                : lane_bcast(aeps_hi, i - 64);
                            float f1 = ((const float*)&c1)[e];
                            float f2 = ((const float*)&c2)[e];
                            m1 = fmaxf(m1, fabsf(fmaf(f1, dl, sv)) - ae);
                            m2 = fmaxf(m2, fabsf(fmaf(f2, dh, sv)) - ae);
                        }
                    }
                }
                judge = ((__ballot(m1 < 0.0f) | __ballot(m2 < 0.0f)) != 0ull);
            }

            if (judge) {
                // ---- Gauss-Seidel sweep (ascending j, violators only) ----
                uint64_t rem_lo = ~0ull, rem_hi = ~0ull;
                while (true) {
                    uint64_t m1b = __ballot((s_lo > a_lo) || (s_lo < -a_lo)) & rem_lo;
                    uint64_t m2b = __ballot((s_hi > a_hi) || (s_hi < -a_hi)) & rem_hi;
                    int j;
                    if (m1b) {
                        int jl = (int)__ffsll((unsigned long long)m1b) - 1;
                        j = jl;
                        rem_lo = (jl == 63) ? 0ull : (~0ull << (jl + 1));
                    } else if (m2b) {
                        int jh = (int)__ffsll((unsigned long long)m2b) - 1;
                        j = 64 + jh;
                        rem_lo = 0ull;
                        rem_hi = (jh == 63) ? 0ull : (~0ull << (jh + 1));
                    } else {
                        break;
                    }
                    float dl2 = (s_lo > a_lo) ? (a_lo - s_lo) * rvd_lo
                               : ((s_lo < -a_lo) ? (-a_lo - s_lo) * rvd_lo : 0.0f);
                    float dh2 = (s_hi > a_hi) ? (a_hi - s_hi) * rvd_hi
                               : ((s_hi < -a_hi) ? (-a_hi - s_hi) * rvd_hi : 0.0f);
                    float srcv = (j < 64) ? dl2 : dh2;
                    float dj = lane_bcast(srcv, j & 63);
                    if (lane == (j & 63)) {
                        if (j < 64) h_lo += dj; else h_hi += dj;
                    }
                    int cjj = (j & 7) << 2;
                    int base = j * 128 + (rlo ^ cjj);
                    s_lo = fmaf(vsh[base], dj, s_lo);
                    s_hi = fmaf(vsh[base + 64], dj, s_hi);
                }
            } else {
                // ---- bisection between pi_bar (s=0) and adj (s), s-space ----
                float hin_lo = tgt_lo, hin_hi = tgt_hi;
                float sin_lo = 0.0f, sin_hi = 0.0f;
                float hout_lo = h_lo, hout_hi = h_hi;
                float sout_lo = s_lo, sout_hi = s_hi;
                float hm_lo = 0.0f, hm_hi = 0.0f;
#pragma unroll
                for (int it = 0; it < 10; ++it) {
                    hm_lo = hin_lo + (hout_lo - hin_lo) * 0.5f;
                    hm_hi = hin_hi + (hout_hi - hin_hi) * 0.5f;
                    float sm_lo = sin_lo + (sout_lo - sin_lo) * 0.5f;
                    float sm_hi = sin_hi + (sout_hi - sin_hi) * 0.5f;
                    bool pl = (sm_lo <= aeps_lo) && (sm_lo >= -aeps_lo);
                    bool ph = (sm_hi <= aeps_hi) && (sm_hi >= -aeps_hi);
                    bool inside = (__ballot(pl && ph) == ~0ull);
                    if (inside) {
                        hin_lo = hm_lo; hin_hi = hm_hi;
                        sin_lo = sm_lo; sin_hi = sm_hi;
                    } else {
                        hout_lo = hm_lo; hout_hi = hm_hi;
                        sout_lo = sm_lo; sout_hi = sm_hi;
                    }
                }
                h_lo = hm_lo;
                h_hi = hm_hi;
            }
        }
        // else: no violators -> judge=1, sweep is a no-op, h unchanged

        out[rlo * T * B + t * B + b] = h_lo;
        out[rhi * T * B + t * B + b] = h_hi;
    }

    out[D * T * B + rlo * B + b] = h_lo;
    out[D * T * B + rhi * B + b] = h_hi;
}

extern "C" void kernel_launch(void* const* d_in, const int* in_sizes, int n_in,
                              void* d_out, int out_size, void* d_ws, size_t ws_size,
                              hipStream_t stream) {
    const float* input   = (const float*)d_in[0];
    const float* target  = (const float*)d_in[1];
    const float* returns = (const float*)d_in[2];
    // d_in[3] = hidden (unused by the reference)
    const float* W = (const float*)d_in[4];
    const float* b = (const float*)d_in[5];
    float* out = (float*)d_out;

    float* vT   = (float*)d_ws;            // 16384 floats
    float* vd   = vT + D * D;              // 128 floats
    float* absb = vd + D;                  // 128 floats

    prep_kernel<<<D, 64, 0, stream>>>(W, b, vT, vd, absb);
    rnn_kernel<<<B / 2, 128, 0, stream>>>(input, target, returns, vT, vd, absb, out);
}